// Round 1
// baseline (2449.236 us; speedup 1.0000x reference)
//
#include <hip/hip_runtime.h>
#include <math.h>

// QuantumAttention fp32 baseline.
// B=2 S=2048 H=1024 NH=16 DH=64. Output = normed(4.19M) ++ probs(134.2M) fp32.
// Workspace layout (floats): qr | qi | kr | ki | vm | lsum   (ctx aliases qr)
//   needs 5*4194304 + 65536 floats = 84.2 MB of d_ws.

#define B_  2
#define S_  2048
#define H_  1024
#define NH_ 16
#define DH_ 64
#define NELEM    4194304   // B*NH*S*DH
#define NORMEDSZ 4194304   // B*S*H

// ---------------------------------------------------------------------------
// K1: per (b, h, 32-token tile): c = x@W+b ; (r,i)/=|.| ; complex rotate by U.
// Weights read through L1 (vector loads, j-coalesced); x/r/i tiles in LDS.
// ---------------------------------------------------------------------------
__global__ __launch_bounds__(256, 4) void k_prep_gate(
    const float* __restrict__ hidden,
    const float* __restrict__ Wq, const float* __restrict__ bq,
    const float* __restrict__ Wk, const float* __restrict__ bk,
    const float* __restrict__ Wv, const float* __restrict__ bv,
    const float* __restrict__ Uqr, const float* __restrict__ Uqi,
    const float* __restrict__ Ukr, const float* __restrict__ Uki,
    const float* __restrict__ Uvr, const float* __restrict__ Uvi,
    float* __restrict__ qr, float* __restrict__ qi,
    float* __restrict__ kr, float* __restrict__ ki,
    float* __restrict__ vm)
{
  const int bid = blockIdx.x;          // 2*16*64 = 2048 blocks
  const int st  = bid & 63;
  const int h   = (bid >> 6) & 15;
  const int b   = bid >> 10;
  const int s0  = st * 32;
  const int tid = threadIdx.x;
  const int j   = tid & 63;
  const int tg  = tid >> 6;            // wave id: uniform -> LDS broadcast reads

  __shared__ float xs[32][64];
  __shared__ float rb[32][64];
  __shared__ float ib[32][64];

  for (int i = 0; i < 8; ++i) {
    int f = tid + i * 256;
    int t = f >> 6, d = f & 63;
    xs[t][d] = hidden[((b * S_ + s0 + t) * H_) + h * 64 + d];
  }
  __syncthreads();

  const float* Ws[3]  = {Wq, Wk, Wv};
  const float* bs[3]  = {bq, bk, bv};
  const float* Urs[3] = {Uqr, Ukr, Uvr};
  const float* Uis[3] = {Uqi, Uki, Uvi};
  const int head = ((b * NH_ + h) * S_) * DH_;

  for (int m = 0; m < 3; ++m) {
    const float* W  = Ws[m];
    const float* bb = bs[m];
    const float* Ur = Urs[m];
    const float* Ui = Uis[m];

    float cr[8], ci[8];
    const float bj0 = bb[j], bj1 = bb[64 + j];
#pragma unroll
    for (int p = 0; p < 8; ++p) { cr[p] = bj0; ci[p] = bj1; }
    for (int d = 0; d < 64; ++d) {
      float wr = W[d * 128 + j];
      float wi = W[d * 128 + 64 + j];
#pragma unroll
      for (int p = 0; p < 8; ++p) {
        float x = xs[tg * 8 + p][d];
        cr[p] = fmaf(x, wr, cr[p]);
        ci[p] = fmaf(x, wi, ci[p]);
      }
    }
#pragma unroll
    for (int p = 0; p < 8; ++p) {
      float inv = rsqrtf(cr[p] * cr[p] + ci[p] * ci[p] + 1e-12f);
      rb[tg * 8 + p][j] = cr[p] * inv;
      ib[tg * 8 + p][j] = ci[p] * inv;
    }
    __syncthreads();

    float gr[8] = {0.f,0.f,0.f,0.f,0.f,0.f,0.f,0.f};
    float gi[8] = {0.f,0.f,0.f,0.f,0.f,0.f,0.f,0.f};
    for (int d = 0; d < 64; ++d) {
      float ur = Ur[d * 64 + j];
      float ui = Ui[d * 64 + j];
#pragma unroll
      for (int p = 0; p < 8; ++p) {
        float rv = rb[tg * 8 + p][d];
        float iv = ib[tg * 8 + p][d];
        gr[p] = fmaf(rv, ur, fmaf(-iv, ui, gr[p]));
        gi[p] = fmaf(rv, ui, fmaf( iv, ur, gi[p]));
      }
    }
#pragma unroll
    for (int p = 0; p < 8; ++p) {
      int t = tg * 8 + p;
      int off = head + (s0 + t) * DH_ + j;
      if (m == 0)      { qr[off] = gr[p]; qi[off] = gi[p]; }
      else if (m == 1) { kr[off] = gr[p]; ki[off] = gi[p]; }
      else             { vm[off] = sqrtf(gr[p] * gr[p] + gi[p] * gi[p]); }
    }
    __syncthreads();  // rb/ib reused next stage
  }
}

// ---------------------------------------------------------------------------
// K2: complex QK^T -> |.|*scale -> threshold -> raw score to probs region,
// plus per-row sum of exp (scores in [0,8] so no max-subtraction needed).
// Block: (bh, 32 q-rows); k-loop over 64-col tiles; thread = 2 rows x 4 cols
// (cols cg, cg+16, cg+32, cg+48 -> 2-way-max LDS bank aliasing, free).
// ---------------------------------------------------------------------------
#define KST 68   // LDS row stride (floats): 16B-aligned rows, benign banks

__device__ __forceinline__ void cfma4(const float4 a, const float4 b,
                                      const float4 x, const float4 y,
                                      float& sr, float& si) {
  sr = fmaf(a.x, x.x, sr); sr = fmaf(-b.x, y.x, sr);
  sr = fmaf(a.y, x.y, sr); sr = fmaf(-b.y, y.y, sr);
  sr = fmaf(a.z, x.z, sr); sr = fmaf(-b.z, y.z, sr);
  sr = fmaf(a.w, x.w, sr); sr = fmaf(-b.w, y.w, sr);
  si = fmaf(a.x, y.x, si); si = fmaf(b.x, x.x, si);
  si = fmaf(a.y, y.y, si); si = fmaf(b.y, x.y, si);
  si = fmaf(a.z, y.z, si); si = fmaf(b.z, x.z, si);
  si = fmaf(a.w, y.w, si); si = fmaf(b.w, x.w, si);
}

__global__ __launch_bounds__(256, 3) void k_scores(
    const float* __restrict__ qr, const float* __restrict__ qi,
    const float* __restrict__ kr, const float* __restrict__ ki,
    float* __restrict__ praw, float* __restrict__ lsum)
{
  const int bid = blockIdx.x;          // 32 bh * 64 qtiles = 2048
  const int qt  = bid & 63;
  const int bh  = bid >> 6;
  const int q0  = qt * 32;
  const int tid = threadIdx.x;
  const int rg  = tid >> 4;            // 0..15 -> rows 2rg, 2rg+1
  const int cg  = tid & 15;            // cols cg + 16*l
  const int r0  = rg * 2;
  const int head = bh * (S_ * DH_);

  __shared__ __align__(16) float sqr[32 * KST];
  __shared__ __align__(16) float sqi[32 * KST];
  __shared__ __align__(16) float skr[64 * KST];
  __shared__ __align__(16) float ski[64 * KST];
  __shared__ float lsh[32];
  if (tid < 32) lsh[tid] = 0.f;

  for (int i = 0; i < 2; ++i) {        // stage q tile (32x64) as float4
    int g = tid + i * 256;
    int r = g >> 4, dq = g & 15;
    *(float4*)(sqr + r * KST + dq * 4) =
        *(const float4*)(qr + head + (q0 + r) * 64 + dq * 4);
    *(float4*)(sqi + r * KST + dq * 4) =
        *(const float4*)(qi + head + (q0 + r) * 64 + dq * 4);
  }

  float lacc0 = 0.f, lacc1 = 0.f;

  for (int kt = 0; kt < 32; ++kt) {
    __syncthreads();
    for (int i = 0; i < 4; ++i) {      // stage k tile (64x64) as float4
      int g = tid + i * 256;
      int c = g >> 4, dq = g & 15;
      *(float4*)(skr + c * KST + dq * 4) =
          *(const float4*)(kr + head + (kt * 64 + c) * 64 + dq * 4);
      *(float4*)(ski + c * KST + dq * 4) =
          *(const float4*)(ki + head + (kt * 64 + c) * 64 + dq * 4);
    }
    __syncthreads();

    float sr[2][4] = {{0.f,0.f,0.f,0.f},{0.f,0.f,0.f,0.f}};
    float si[2][4] = {{0.f,0.f,0.f,0.f},{0.f,0.f,0.f,0.f}};
    for (int d0 = 0; d0 < 16; ++d0) {
      const float4 a0 = *(const float4*)(sqr + r0 * KST + d0 * 4);
      const float4 a1 = *(const float4*)(sqr + (r0 + 1) * KST + d0 * 4);
      const float4 b0 = *(const float4*)(sqi + r0 * KST + d0 * 4);
      const float4 b1 = *(const float4*)(sqi + (r0 + 1) * KST + d0 * 4);
#pragma unroll
      for (int l = 0; l < 4; ++l) {
        const int c = cg + 16 * l;
        const float4 x = *(const float4*)(skr + c * KST + d0 * 4);
        const float4 y = *(const float4*)(ski + c * KST + d0 * 4);
        cfma4(a0, b0, x, y, sr[0][l], si[0][l]);
        cfma4(a1, b1, x, y, sr[1][l], si[1][l]);
      }
    }

    const size_t rowbase = ((size_t)bh * S_ + (q0 + r0)) * S_ + kt * 64;
#pragma unroll
    for (int jr = 0; jr < 2; ++jr) {
      float e = 0.f;
#pragma unroll
      for (int l = 0; l < 4; ++l) {
        float mg2 = sr[jr][l] * sr[jr][l] + si[jr][l] * si[jr][l];
        float m = sqrtf(mg2) * 0.125f;
        m = (m < 0.1f) ? 0.f : m;
        praw[rowbase + (size_t)jr * S_ + cg + 16 * l] = m;
        e += __expf(m);
      }
      if (jr == 0) lacc0 += e; else lacc1 += e;
    }
  }

  atomicAdd(&lsh[r0],     lacc0);
  atomicAdd(&lsh[r0 + 1], lacc1);
  __syncthreads();
  if (tid < 32) lsum[bh * S_ + q0 + tid] = lsh[tid];
}

// ---------------------------------------------------------------------------
// K3: read raw scores, p = exp(s)/l (same __expf bits as K2 -> consistent),
// write normalized probs in-place, fused PV: ctx = P @ |V|  (ctx in [B,S,H]).
// Block: (bh, 64 q-rows); thread = 4 rows x 4 dims.
// ---------------------------------------------------------------------------
#define SPST 65

__global__ __launch_bounds__(256, 4) void k_pv(
    const float* __restrict__ vm, const float* __restrict__ lsum,
    float* __restrict__ probs, float* __restrict__ ctx)
{
  const int bid = blockIdx.x;          // 32 bh * 32 qtiles = 1024
  const int qt  = bid & 31;
  const int bh  = bid >> 5;
  const int q0  = qt * 64;
  const int b   = bh >> 4, h = bh & 15;
  const int tid = threadIdx.x;
  const int rg  = tid >> 4;            // rows r0 = 4*rg .. +3
  const int dg  = tid & 15;            // dims d0 = 4*dg .. +3
  const int r0  = rg * 4;
  const int d0  = dg * 4;
  const int head = bh * (S_ * DH_);

  __shared__ float sp[64 * SPST];
  __shared__ __align__(16) float svm[64 * 64];
  __shared__ float rinv[64];
  if (tid < 64) rinv[tid] = 1.f / lsum[bh * S_ + q0 + tid];

  float acc[4][4] = {{0.f,0.f,0.f,0.f},{0.f,0.f,0.f,0.f},
                     {0.f,0.f,0.f,0.f},{0.f,0.f,0.f,0.f}};

  for (int kt = 0; kt < 32; ++kt) {
    __syncthreads();
    for (int i = 0; i < 16; ++i) {     // normalize 64x64 tile, stash in LDS
      int f = tid + i * 256;
      int r = f >> 6, c = f & 63;
      size_t off = ((size_t)bh * S_ + q0 + r) * S_ + kt * 64 + c;
      float p = __expf(probs[off]) * rinv[r];
      probs[off] = p;
      sp[r * SPST + c] = p;
    }
    for (int i = 0; i < 4; ++i) {      // stage |V| tile (64x64)
      int g = tid + i * 256;
      int c = g >> 4, dq = g & 15;
      *(float4*)(svm + c * 64 + dq * 4) =
          *(const float4*)(vm + head + (kt * 64 + c) * 64 + dq * 4);
    }
    __syncthreads();

    for (int ck = 0; ck < 64; ++ck) {
      const float4 v4 = *(const float4*)(svm + ck * 64 + d0);
#pragma unroll
      for (int jr = 0; jr < 4; ++jr) {
        float p = sp[(r0 + jr) * SPST + ck];
        acc[jr][0] = fmaf(p, v4.x, acc[jr][0]);
        acc[jr][1] = fmaf(p, v4.y, acc[jr][1]);
        acc[jr][2] = fmaf(p, v4.z, acc[jr][2]);
        acc[jr][3] = fmaf(p, v4.w, acc[jr][3]);
      }
    }
  }
#pragma unroll
  for (int jr = 0; jr < 4; ++jr) {
    float4 o;
    o.x = acc[jr][0]; o.y = acc[jr][1]; o.z = acc[jr][2]; o.w = acc[jr][3];
    *(float4*)(ctx + (size_t)(b * S_ + q0 + r0 + jr) * H_ + h * 64 + d0) = o;
  }
}

// ---------------------------------------------------------------------------
// K4: res = ctx @ Wo + bo + hidden   (64x64 tile, K-tile 32, 4x4 micro)
// ---------------------------------------------------------------------------
#define AST 36
#define BST 68

__global__ __launch_bounds__(256, 4) void k_out_gemm(
    const float* __restrict__ ctx, const float* __restrict__ Wo,
    const float* __restrict__ bo, const float* __restrict__ hidden,
    float* __restrict__ res)
{
  const int bid = blockIdx.x;          // 64 mtiles * 16 ntiles = 1024
  const int nt  = bid & 15;
  const int mt  = bid >> 4;
  const int m0  = mt * 64, n0 = nt * 64;
  const int tid = threadIdx.x;
  const int mg  = tid >> 4, ng = tid & 15;

  __shared__ __align__(16) float sa[64 * AST];
  __shared__ __align__(16) float sb[32 * BST];

  float acc[4][4] = {{0.f,0.f,0.f,0.f},{0.f,0.f,0.f,0.f},
                     {0.f,0.f,0.f,0.f},{0.f,0.f,0.f,0.f}};

  for (int kt = 0; kt < 32; ++kt) {
    __syncthreads();
    for (int i = 0; i < 2; ++i) {      // a tile 64x32
      int g = tid + i * 256;
      int r = g >> 3, dq = g & 7;
      *(float4*)(sa + r * AST + dq * 4) =
          *(const float4*)(ctx + (size_t)(m0 + r) * H_ + kt * 32 + dq * 4);
    }
    for (int i = 0; i < 2; ++i) {      // b tile 32x64
      int g = tid + i * 256;
      int r = g >> 4, dq = g & 15;
      *(float4*)(sb + r * BST + dq * 4) =
          *(const float4*)(Wo + (size_t)(kt * 32 + r) * H_ + n0 + dq * 4);
    }
    __syncthreads();

    for (int kk = 0; kk < 32; ++kk) {
      const float4 b4 = *(const float4*)(sb + kk * BST + ng * 4);
      const float a0 = sa[(mg * 4 + 0) * AST + kk];
      const float a1 = sa[(mg * 4 + 1) * AST + kk];
      const float a2 = sa[(mg * 4 + 2) * AST + kk];
      const float a3 = sa[(mg * 4 + 3) * AST + kk];
      acc[0][0] = fmaf(a0, b4.x, acc[0][0]); acc[0][1] = fmaf(a0, b4.y, acc[0][1]);
      acc[0][2] = fmaf(a0, b4.z, acc[0][2]); acc[0][3] = fmaf(a0, b4.w, acc[0][3]);
      acc[1][0] = fmaf(a1, b4.x, acc[1][0]); acc[1][1] = fmaf(a1, b4.y, acc[1][1]);
      acc[1][2] = fmaf(a1, b4.z, acc[1][2]); acc[1][3] = fmaf(a1, b4.w, acc[1][3]);
      acc[2][0] = fmaf(a2, b4.x, acc[2][0]); acc[2][1] = fmaf(a2, b4.y, acc[2][1]);
      acc[2][2] = fmaf(a2, b4.z, acc[2][2]); acc[2][3] = fmaf(a2, b4.w, acc[2][3]);
      acc[3][0] = fmaf(a3, b4.x, acc[3][0]); acc[3][1] = fmaf(a3, b4.y, acc[3][1]);
      acc[3][2] = fmaf(a3, b4.z, acc[3][2]); acc[3][3] = fmaf(a3, b4.w, acc[3][3]);
    }
  }

  const float4 bo4 = *(const float4*)(bo + n0 + ng * 4);
#pragma unroll
  for (int jm = 0; jm < 4; ++jm) {
    int m = m0 + mg * 4 + jm;
    const float4 hv = *(const float4*)(hidden + (size_t)m * H_ + n0 + ng * 4);
    float4 o;
    o.x = acc[jm][0] + bo4.x + hv.x;
    o.y = acc[jm][1] + bo4.y + hv.y;
    o.z = acc[jm][2] + bo4.z + hv.z;
    o.w = acc[jm][3] + bo4.w + hv.w;
    *(float4*)(res + (size_t)m * H_ + n0 + ng * 4) = o;
  }
}

// ---------------------------------------------------------------------------
// K5: in-place LayerNorm over H=1024 per token (eps inside sqrt, as ref)
// ---------------------------------------------------------------------------
__global__ __launch_bounds__(256, 4) void k_layernorm(
    const float* __restrict__ gamma, const float* __restrict__ beta,
    float* __restrict__ out)
{
  const int t   = blockIdx.x;          // 4096 tokens
  const int tid = threadIdx.x;
  float4 x = *(const float4*)(out + (size_t)t * H_ + tid * 4);
  float s = x.x + x.y + x.z + x.w;
  float q = x.x * x.x + x.y * x.y + x.z * x.z + x.w * x.w;
  for (int off = 32; off > 0; off >>= 1) {
    s += __shfl_down(s, off, 64);
    q += __shfl_down(q, off, 64);
  }
  __shared__ float red[8];
  int wid = tid >> 6;
  if ((tid & 63) == 0) { red[wid] = s; red[4 + wid] = q; }
  __syncthreads();
  s = red[0] + red[1] + red[2] + red[3];
  q = red[4] + red[5] + red[6] + red[7];
  const float mu  = s * (1.f / 1024.f);
  const float var = fmaxf(q * (1.f / 1024.f) - mu * mu, 0.f);
  const float rstd = rsqrtf(var + 1e-12f);
  const float4 g4 = *(const float4*)(gamma + tid * 4);
  const float4 b4 = *(const float4*)(beta + tid * 4);
  float4 o;
  o.x = (x.x - mu) * rstd * g4.x + b4.x;
  o.y = (x.y - mu) * rstd * g4.y + b4.y;
  o.z = (x.z - mu) * rstd * g4.z + b4.z;
  o.w = (x.w - mu) * rstd * g4.w + b4.w;
  *(float4*)(out + (size_t)t * H_ + tid * 4) = o;
}

// ---------------------------------------------------------------------------
extern "C" void kernel_launch(void* const* d_in, const int* in_sizes, int n_in,
                              void* d_out, int out_size, void* d_ws, size_t ws_size,
                              hipStream_t stream) {
  (void)in_sizes; (void)n_in; (void)out_size; (void)ws_size;

  const float* hidden = (const float*)d_in[0];
  const float* Wq  = (const float*)d_in[1];  const float* bq = (const float*)d_in[2];
  const float* Wk  = (const float*)d_in[3];  const float* bk = (const float*)d_in[4];
  const float* Wv  = (const float*)d_in[5];  const float* bv = (const float*)d_in[6];
  const float* Uqr = (const float*)d_in[7];  const float* Uqi = (const float*)d_in[8];
  const float* Ukr = (const float*)d_in[9];  const float* Uki = (const float*)d_in[10];
  const float* Uvr = (const float*)d_in[11]; const float* Uvi = (const float*)d_in[12];
  const float* Wo  = (const float*)d_in[13]; const float* bo = (const float*)d_in[14];
  const float* gamma = (const float*)d_in[15];
  const float* beta  = (const float*)d_in[16];

  float* outp  = (float*)d_out;            // normed [B,S,H]
  float* probs = outp + NORMEDSZ;          // probs  [B,NH,S,S]

  float* ws = (float*)d_ws;
  float* qr = ws;
  float* qi = ws + (size_t)NELEM;
  float* kr = ws + 2 * (size_t)NELEM;
  float* ki = ws + 3 * (size_t)NELEM;
  float* vm = ws + 4 * (size_t)NELEM;
  float* ls = ws + 5 * (size_t)NELEM;      // [B*NH*S] row exp-sums
  float* ctx = qr;                          // alias: qr dead after k_scores

  k_prep_gate<<<2048, 256, 0, stream>>>(hidden, Wq, bq, Wk, bk, Wv, bv,
                                        Uqr, Uqi, Ukr, Uki, Uvr, Uvi,
                                        qr, qi, kr, ki, vm);
  k_scores<<<2048, 256, 0, stream>>>(qr, qi, kr, ki, probs, ls);
  k_pv<<<1024, 256, 0, stream>>>(vm, ls, probs, ctx);
  k_out_gemm<<<1024, 256, 0, stream>>>(ctx, Wo, bo, hidden, outp);
  k_layernorm<<<4096, 256, 0, stream>>>(gamma, beta, outp);
}